// Round 1
// baseline (3259.650 us; speedup 1.0000x reference)
//
#include <hip/hip_runtime.h>

// Problem constants (from reference setup_inputs)
#define N_NODES  50000
#define N_EDGES  640000
#define N_GRAPHS 500
static constexpr float BN_EPS = 1e-5f;

// ---------------------------------------------------------------------------
// deg[dst] += w  (self-loop +1 added in k_dinv)
__global__ void k_deg(const int* __restrict__ dst, const float* __restrict__ w,
                      float* __restrict__ deg, int E) {
    int i = blockIdx.x * blockDim.x + threadIdx.x;
    if (i < E) atomicAdd(&deg[dst[i]], w[i]);
}

// deg -> dinv = rsqrt(deg + 1)
__global__ void k_dinv(float* __restrict__ deg, int n) {
    int i = blockIdx.x * blockDim.x + threadIdx.x;
    if (i < n) deg[i] = rsqrtf(deg[i] + 1.0f);
}

// norm[e] = dinv[src]*w*dinv[dst]
__global__ void k_norm(const int* __restrict__ src, const int* __restrict__ dst,
                       const float* __restrict__ w, const float* __restrict__ dinv,
                       float* __restrict__ nrm, int E) {
    int i = blockIdx.x * blockDim.x + threadIdx.x;
    if (i < E) nrm[i] = dinv[src[i]] * w[i] * dinv[dst[i]];
}

// ---------------------------------------------------------------------------
// H = X @ W  (X: n x K row-major, W: K x C row-major). Thread per (row, c).
// Consecutive threads share `row` (uniform X load) and have consecutive c
// (coalesced W load; W is tiny and cache-resident).
template <int K, int C>
__global__ void k_mm(const float* __restrict__ X, const float* __restrict__ W,
                     float* __restrict__ H, int n) {
    int gid = blockIdx.x * blockDim.x + threadIdx.x;
    if (gid >= n * C) return;
    int row = gid / C;
    int c   = gid % C;
    const float* xr = X + row * K;
    float acc = 0.f;
#pragma unroll 8
    for (int k = 0; k < K; ++k) acc += xr[k] * W[k * C + c];
    H[gid] = acc;
}

// ---------------------------------------------------------------------------
// Edge scatter: A[dst,:] += H[src,:] * norm[e].  C/4 threads per edge, each
// handling 4 contiguous channels (float4 gather, 4 atomics to contiguous addrs).
template <int C>
__global__ void k_scatter(const int* __restrict__ src, const int* __restrict__ dst,
                          const float* __restrict__ nrm, const float* __restrict__ H,
                          float* __restrict__ A, int E) {
    constexpr int TPE = C / 4;
    int gid = blockIdx.x * blockDim.x + threadIdx.x;
    if (gid >= E * TPE) return;
    int e = gid / TPE;
    int t = gid % TPE;
    int s = src[e];
    int d = dst[e];
    float nm = nrm[e];
    float4 hv = *(const float4*)(H + s * C + t * 4);
    float* out = A + d * C + t * 4;
    atomicAdd(out + 0, hv.x * nm);
    atomicAdd(out + 1, hv.y * nm);
    atomicAdd(out + 2, hv.z * nm);
    atomicAdd(out + 3, hv.w * nm);
}

// ---------------------------------------------------------------------------
// out = relu( bn( agg + H*dinv^2 + b ) ) [+ res]; may alias out==agg.
template <int C, bool RES>
__global__ void k_bnrelu(const float* __restrict__ agg, const float* __restrict__ H,
                         const float* __restrict__ dinv, const float* __restrict__ b,
                         const float* __restrict__ g, const float* __restrict__ be,
                         const float* __restrict__ m, const float* __restrict__ v,
                         const float* __restrict__ res, float* __restrict__ out, int n) {
    int gid = blockIdx.x * blockDim.x + threadIdx.x;
    if (gid >= n * C) return;
    int row = gid / C;
    int c   = gid % C;
    float di  = dinv[row];
    float val = agg[gid] + H[gid] * di * di + b[c];
    val = (val - m[c]) * rsqrtf(v[c] + BN_EPS) * g[c] + be[c];
    val = fmaxf(val, 0.f);
    if (RES) val += res[gid];
    out[gid] = val;
}

// ---------------------------------------------------------------------------
// pooled[batch[n], c] += A[n, c]; cnt[batch[n]] += 1 (once per node)
__global__ void k_pool(const float* __restrict__ A, const int* __restrict__ batch,
                       float* __restrict__ pooled, float* __restrict__ cnt, int n) {
    int gid = blockIdx.x * blockDim.x + threadIdx.x;
    if (gid >= n * 128) return;
    int row = gid >> 7;
    int c   = gid & 127;
    int grp = batch[row];
    atomicAdd(&pooled[grp * 128 + c], A[gid]);
    if (c == 0) atomicAdd(&cnt[grp], 1.0f);
}

// out[g] = dot(pooled[g,:], Wf) / max(cnt,1) + bf
__global__ void k_final(const float* __restrict__ pooled, const float* __restrict__ cnt,
                        const float* __restrict__ Wf, const float* __restrict__ bf,
                        float* __restrict__ out, int G) {
    int g = blockIdx.x * blockDim.x + threadIdx.x;
    if (g >= G) return;
    float s = 0.f;
    for (int c = 0; c < 128; ++c) s += pooled[g * 128 + c] * Wf[c];
    out[g] = s / fmaxf(cnt[g], 1.0f) + bf[0];
}

// ---------------------------------------------------------------------------
extern "C" void kernel_launch(void* const* d_in, const int* in_sizes, int n_in,
                              void* d_out, int out_size, void* d_ws, size_t ws_size,
                              hipStream_t stream) {
    const float* x    = (const float*)d_in[0];
    const int*   ei   = (const int*)d_in[1];
    const int*   src  = ei;
    const int*   dst  = ei + N_EDGES;
    const float* w    = (const float*)d_in[2];
    const int*   batch = (const int*)d_in[3];
    const float* W1 = (const float*)d_in[4];
    const float* b1 = (const float*)d_in[5];
    const float* W2 = (const float*)d_in[6];
    const float* b2 = (const float*)d_in[7];
    const float* W3 = (const float*)d_in[8];
    const float* b3 = (const float*)d_in[9];
    const float* Wf = (const float*)d_in[10];
    const float* bf = (const float*)d_in[11];
    const float* g1 = (const float*)d_in[12];
    const float* be1 = (const float*)d_in[13];
    const float* m1 = (const float*)d_in[14];
    const float* v1 = (const float*)d_in[15];
    const float* g2 = (const float*)d_in[16];
    const float* be2 = (const float*)d_in[17];
    const float* m2 = (const float*)d_in[18];
    const float* v2 = (const float*)d_in[19];
    const float* g3 = (const float*)d_in[20];
    const float* be3 = (const float*)d_in[21];
    const float* m3 = (const float*)d_in[22];
    const float* v3 = (const float*)d_in[23];

    float* out = (float*)d_out;

    // Workspace layout (floats)
    float* ws    = (float*)d_ws;
    float* dinv  = ws;                       // N  (holds deg, then dinv)
    float* nrm   = dinv + N_NODES;           // E
    float* H     = nrm + N_EDGES;            // N*128 (XW of current layer)
    float* A     = H + (size_t)N_NODES * 128;  // N*128
    float* B     = A + (size_t)N_NODES * 128;  // N*128
    float* pooled = B + (size_t)N_NODES * 128; // G*128
    float* cnt   = pooled + (size_t)N_GRAPHS * 128; // G  (contiguous with pooled)

    const int BS = 256;
    auto nb = [](long n) { return (int)((n + 255) / 256); };

    // --- degree / norm precompute (shared across all 3 layers) ---
    hipMemsetAsync(dinv, 0, N_NODES * sizeof(float), stream);
    k_deg<<<nb(N_EDGES), BS, 0, stream>>>(dst, w, dinv, N_EDGES);
    k_dinv<<<nb(N_NODES), BS, 0, stream>>>(dinv, N_NODES);
    k_norm<<<nb(N_EDGES), BS, 0, stream>>>(src, dst, w, dinv, nrm, N_EDGES);

    // --- Layer 1: 1 -> 64 ---
    k_mm<1, 64><<<nb((long)N_NODES * 64), BS, 0, stream>>>(x, W1, H, N_NODES);
    hipMemsetAsync(A, 0, (size_t)N_NODES * 64 * sizeof(float), stream);
    k_scatter<64><<<nb((long)N_EDGES * 16), BS, 0, stream>>>(src, dst, nrm, H, A, N_EDGES);
    k_bnrelu<64, false><<<nb((long)N_NODES * 64), BS, 0, stream>>>(
        A, H, dinv, b1, g1, be1, m1, v1, nullptr, A, N_NODES);

    // --- Layer 2: 64 -> 128 ---
    k_mm<64, 128><<<nb((long)N_NODES * 128), BS, 0, stream>>>(A, W2, H, N_NODES);
    hipMemsetAsync(B, 0, (size_t)N_NODES * 128 * sizeof(float), stream);
    k_scatter<128><<<nb((long)N_EDGES * 32), BS, 0, stream>>>(src, dst, nrm, H, B, N_EDGES);
    k_bnrelu<128, false><<<nb((long)N_NODES * 128), BS, 0, stream>>>(
        B, H, dinv, b2, g2, be2, m2, v2, nullptr, B, N_NODES);
    // B now holds res (layer-2 output)

    // --- Layer 3: 128 -> 128, + residual ---
    k_mm<128, 128><<<nb((long)N_NODES * 128), BS, 0, stream>>>(B, W3, H, N_NODES);
    hipMemsetAsync(A, 0, (size_t)N_NODES * 128 * sizeof(float), stream);
    k_scatter<128><<<nb((long)N_EDGES * 32), BS, 0, stream>>>(src, dst, nrm, H, A, N_EDGES);
    k_bnrelu<128, true><<<nb((long)N_NODES * 128), BS, 0, stream>>>(
        A, H, dinv, b3, g3, be3, m3, v3, B, A, N_NODES);

    // --- global mean pool + final linear ---
    hipMemsetAsync(pooled, 0, (size_t)N_GRAPHS * 129 * sizeof(float), stream);
    k_pool<<<nb((long)N_NODES * 128), BS, 0, stream>>>(A, batch, pooled, cnt, N_NODES);
    k_final<<<nb(N_GRAPHS), BS, 0, stream>>>(pooled, cnt, Wf, bf, out, N_GRAPHS);
}

// Round 2
// 781.450 us; speedup vs baseline: 4.1713x; 4.1713x over previous
//
#include <hip/hip_runtime.h>

// Problem constants (from reference setup_inputs)
#define N_NODES  50000
#define N_EDGES  640000
#define N_GRAPHS 500
static constexpr float BN_EPS = 1e-5f;

// ---------------------------------------------------------------------------
// Per-destination weighted degree (float) and edge count (int) in one pass.
__global__ void k_degcnt(const int* __restrict__ dst, const float* __restrict__ w,
                         float* __restrict__ wdeg, int* __restrict__ cnt, int E) {
    int i = blockIdx.x * blockDim.x + threadIdx.x;
    if (i < E) {
        int d = dst[i];
        atomicAdd(&wdeg[d], w[i]);
        atomicAdd(&cnt[d], 1);
    }
}

// wdeg -> dinv = rsqrt(wdeg + 1)   (self-loop weight 1)
__global__ void k_dinv(float* __restrict__ wdeg, int n) {
    int i = blockIdx.x * blockDim.x + threadIdx.x;
    if (i < n) wdeg[i] = rsqrtf(wdeg[i] + 1.0f);
}

// Single-block exclusive scan of cnt[n] -> offs[n+1]; also copies into cursor.
__global__ void k_scan(const int* __restrict__ cnt, int* __restrict__ offs,
                       int* __restrict__ cursor, int n) {
    __shared__ int part[1024];
    int t = threadIdx.x;
    int chunk = (n + 1023) / 1024;
    int base = t * chunk;
    int s = 0;
    for (int k = 0; k < chunk; ++k) {
        int i = base + k;
        if (i < n) s += cnt[i];
    }
    part[t] = s;
    __syncthreads();
    // Hillis-Steele inclusive scan over 1024 partials
    for (int off = 1; off < 1024; off <<= 1) {
        int v = (t >= off) ? part[t - off] : 0;
        __syncthreads();
        part[t] += v;
        __syncthreads();
    }
    int run = (t == 0) ? 0 : part[t - 1];
    for (int k = 0; k < chunk; ++k) {
        int i = base + k;
        if (i < n) {
            offs[i] = run;
            cursor[i] = run;
            run += cnt[i];
        }
    }
    if (t == 1023) offs[n] = run;
}

// Bucket edges into CSR slots; store src id and precomputed norm.
__global__ void k_fill(const int* __restrict__ src, const int* __restrict__ dst,
                       const float* __restrict__ w, const float* __restrict__ dinv,
                       int* __restrict__ cursor, int* __restrict__ csrc,
                       float* __restrict__ cnrm, int E) {
    int e = blockIdx.x * blockDim.x + threadIdx.x;
    if (e < E) {
        int s = src[e], d = dst[e];
        int pos = atomicAdd(&cursor[d], 1);
        csrc[pos] = s;
        cnrm[pos] = dinv[s] * w[e] * dinv[d];
    }
}

// Fold bias+BN into per-channel affine: y = x*kA + kB
__global__ void k_bnprep(const float* __restrict__ b, const float* __restrict__ g,
                         const float* __restrict__ be, const float* __restrict__ m,
                         const float* __restrict__ v, float* __restrict__ kA,
                         float* __restrict__ kB, int C) {
    int c = threadIdx.x;
    if (c < C) {
        float s = g[c] * rsqrtf(v[c] + BN_EPS);
        kA[c] = s;
        kB[c] = (b[c] - m[c]) * s + be[c];
    }
}

// H[i,c] = x[i] * W[c]   (layer 1, K=1)
__global__ void k_mm1(const float* __restrict__ X, const float* __restrict__ W,
                      float* __restrict__ H, int n) {
    int gid = blockIdx.x * blockDim.x + threadIdx.x;
    if (gid >= n * 64) return;
    int row = gid >> 6;
    int c = gid & 63;
    H[gid] = X[row] * W[c];
}

// H = X @ W, thread computes 4 contiguous outputs (float4 on W rows).
template <int K, int C>
__global__ void k_mm4(const float* __restrict__ X, const float* __restrict__ W,
                      float* __restrict__ H, int n) {
    constexpr int TPR = C / 4;
    int gid = blockIdx.x * blockDim.x + threadIdx.x;
    if (gid >= n * TPR) return;
    int row = gid / TPR;
    int c4 = (gid % TPR) * 4;
    const float* xr = X + (size_t)row * K;
    float4 acc = {0.f, 0.f, 0.f, 0.f};
#pragma unroll 4
    for (int k = 0; k < K; ++k) {
        float xk = xr[k];
        float4 wv = *(const float4*)(W + (size_t)k * C + c4);
        acc.x += xk * wv.x;
        acc.y += xk * wv.y;
        acc.z += xk * wv.z;
        acc.w += xk * wv.w;
    }
    *(float4*)(H + (size_t)row * C + c4) = acc;
}

// ---------------------------------------------------------------------------
// Gather-aggregate + self-loop + affine(BN,bias) + ReLU (+residual) (+pool).
// C/4 threads per node, each owning 4 contiguous channels.
template <int C, bool RES, bool POOL>
__global__ void k_gather(const int* __restrict__ offs, const int* __restrict__ csrc,
                         const float* __restrict__ cnrm, const float* __restrict__ H,
                         const float* __restrict__ dinv, const float* __restrict__ kA,
                         const float* __restrict__ kB, const float* __restrict__ res,
                         float* __restrict__ out, const int* __restrict__ batch,
                         float* __restrict__ pooled, int n) {
    constexpr int TPN = C / 4;
    int gid = blockIdx.x * blockDim.x + threadIdx.x;
    int node = gid / TPN;
    if (node >= n) return;
    int c = (gid % TPN) * 4;

    float4 acc = {0.f, 0.f, 0.f, 0.f};
    int e0 = offs[node], e1 = offs[node + 1];
    for (int j = e0; j < e1; ++j) {
        int s = csrc[j];
        float nm = cnrm[j];
        float4 hv = *(const float4*)(H + (size_t)s * C + c);
        acc.x += hv.x * nm;
        acc.y += hv.y * nm;
        acc.z += hv.z * nm;
        acc.w += hv.w * nm;
    }
    // self-loop
    float di = dinv[node];
    float d2 = di * di;
    float4 hv = *(const float4*)(H + (size_t)node * C + c);
    acc.x += hv.x * d2;
    acc.y += hv.y * d2;
    acc.z += hv.z * d2;
    acc.w += hv.w * d2;
    // affine (bias+BN folded) + relu
    float4 val;
    val.x = fmaxf(acc.x * kA[c + 0] + kB[c + 0], 0.f);
    val.y = fmaxf(acc.y * kA[c + 1] + kB[c + 1], 0.f);
    val.z = fmaxf(acc.z * kA[c + 2] + kB[c + 2], 0.f);
    val.w = fmaxf(acc.w * kA[c + 3] + kB[c + 3], 0.f);
    if (RES) {
        float4 rv = *(const float4*)(res + (size_t)node * C + c);
        val.x += rv.x; val.y += rv.y; val.z += rv.z; val.w += rv.w;
    }
    if (POOL) {
        int grp = batch[node];
        float* p = pooled + (size_t)grp * C + c;
        atomicAdd(p + 0, val.x);
        atomicAdd(p + 1, val.y);
        atomicAdd(p + 2, val.z);
        atomicAdd(p + 3, val.w);
    } else {
        *(float4*)(out + (size_t)node * C + c) = val;
    }
}

// per-graph node counts (float for later divide)
__global__ void k_gcnt(const int* __restrict__ batch, float* __restrict__ gcnt, int n) {
    int i = blockIdx.x * blockDim.x + threadIdx.x;
    if (i < n) atomicAdd(&gcnt[batch[i]], 1.0f);
}

// out[g] = dot(pooled[g,:], Wf) / max(cnt,1) + bf
__global__ void k_final(const float* __restrict__ pooled, const float* __restrict__ gcnt,
                        const float* __restrict__ Wf, const float* __restrict__ bf,
                        float* __restrict__ out, int G) {
    int g = blockIdx.x * blockDim.x + threadIdx.x;
    if (g >= G) return;
    float s = 0.f;
    for (int c = 0; c < 128; ++c) s += pooled[g * 128 + c] * Wf[c];
    out[g] = s / fmaxf(gcnt[g], 1.0f) + bf[0];
}

// ---------------------------------------------------------------------------
extern "C" void kernel_launch(void* const* d_in, const int* in_sizes, int n_in,
                              void* d_out, int out_size, void* d_ws, size_t ws_size,
                              hipStream_t stream) {
    const float* x     = (const float*)d_in[0];
    const int*   ei    = (const int*)d_in[1];
    const int*   src   = ei;
    const int*   dst   = ei + N_EDGES;
    const float* w     = (const float*)d_in[2];
    const int*   batch = (const int*)d_in[3];
    const float* W1 = (const float*)d_in[4];
    const float* b1 = (const float*)d_in[5];
    const float* W2 = (const float*)d_in[6];
    const float* b2 = (const float*)d_in[7];
    const float* W3 = (const float*)d_in[8];
    const float* b3 = (const float*)d_in[9];
    const float* Wf = (const float*)d_in[10];
    const float* bf = (const float*)d_in[11];
    const float* g1 = (const float*)d_in[12];
    const float* be1 = (const float*)d_in[13];
    const float* m1 = (const float*)d_in[14];
    const float* v1 = (const float*)d_in[15];
    const float* g2 = (const float*)d_in[16];
    const float* be2 = (const float*)d_in[17];
    const float* m2 = (const float*)d_in[18];
    const float* v2 = (const float*)d_in[19];
    const float* g3 = (const float*)d_in[20];
    const float* be3 = (const float*)d_in[21];
    const float* m3 = (const float*)d_in[22];
    const float* v3 = (const float*)d_in[23];

    float* out = (float*)d_out;

    // Workspace layout — 16B-aligned sections first, odd-sized int array last.
    float* ws = (float*)d_ws;
    float* H      = ws;                               // N*128
    float* A64    = H + (size_t)N_NODES * 128;        // N*64 (layer-1 output)
    float* B      = A64 + (size_t)N_NODES * 64;       // N*128 (layer-2 output / residual)
    int*   csrc   = (int*)(B + (size_t)N_NODES * 128);// E
    float* cnrm   = (float*)(csrc + N_EDGES);         // E
    float* wdeg   = cnrm + N_EDGES;                   // N (then dinv)
    int*   cnt_i  = (int*)(wdeg + N_NODES);           // N
    int*   cursor = cnt_i + N_NODES;                  // N
    float* kA     = (float*)(cursor + N_NODES);       // 128
    float* kB     = kA + 128;                         // 128
    float* pooled = kB + 128;                         // G*128
    float* gcnt   = pooled + (size_t)N_GRAPHS * 128;  // G
    int*   offs   = (int*)(gcnt + N_GRAPHS);          // N+1

    const int BS = 256;
    auto nb = [](long n) { return (int)((n + 255) / 256); };

    // --- CSR build + degree norm (shared across layers) ---
    hipMemsetAsync(wdeg, 0, N_NODES * sizeof(float), stream);
    hipMemsetAsync(cnt_i, 0, N_NODES * sizeof(int), stream);
    k_degcnt<<<nb(N_EDGES), BS, 0, stream>>>(dst, w, wdeg, cnt_i, N_EDGES);
    k_scan<<<1, 1024, 0, stream>>>(cnt_i, offs, cursor, N_NODES);
    k_dinv<<<nb(N_NODES), BS, 0, stream>>>(wdeg, N_NODES);
    float* dinv = wdeg;
    k_fill<<<nb(N_EDGES), BS, 0, stream>>>(src, dst, w, dinv, cursor, csrc, cnrm, N_EDGES);

    // --- Layer 1: 1 -> 64 ---
    k_mm1<<<nb((long)N_NODES * 64), BS, 0, stream>>>(x, W1, H, N_NODES);
    k_bnprep<<<1, 128, 0, stream>>>(b1, g1, be1, m1, v1, kA, kB, 64);
    k_gather<64, false, false><<<nb((long)N_NODES * 16), BS, 0, stream>>>(
        offs, csrc, cnrm, H, dinv, kA, kB, nullptr, A64, nullptr, nullptr, N_NODES);

    // --- Layer 2: 64 -> 128 ---
    k_mm4<64, 128><<<nb((long)N_NODES * 32), BS, 0, stream>>>(A64, W2, H, N_NODES);
    k_bnprep<<<1, 128, 0, stream>>>(b2, g2, be2, m2, v2, kA, kB, 128);
    k_gather<128, false, false><<<nb((long)N_NODES * 32), BS, 0, stream>>>(
        offs, csrc, cnrm, H, dinv, kA, kB, nullptr, B, nullptr, nullptr, N_NODES);

    // --- Layer 3: 128 -> 128, + residual, fused mean-pool accumulation ---
    k_mm4<128, 128><<<nb((long)N_NODES * 32), BS, 0, stream>>>(B, W3, H, N_NODES);
    k_bnprep<<<1, 128, 0, stream>>>(b3, g3, be3, m3, v3, kA, kB, 128);
    hipMemsetAsync(pooled, 0, (size_t)N_GRAPHS * 129 * sizeof(float), stream); // pooled+gcnt
    k_gather<128, true, true><<<nb((long)N_NODES * 32), BS, 0, stream>>>(
        offs, csrc, cnrm, H, dinv, kA, kB, B, nullptr, batch, pooled, N_NODES);

    // --- counts + final linear ---
    k_gcnt<<<nb(N_NODES), BS, 0, stream>>>(batch, gcnt, N_NODES);
    k_final<<<nb(N_GRAPHS), BS, 0, stream>>>(pooled, gcnt, Wf, bf, out, N_GRAPHS);
}

// Round 3
// 749.439 us; speedup vs baseline: 4.3495x; 1.0427x over previous
//
#include <hip/hip_runtime.h>

#define N_NODES  50000
#define N_EDGES  640000
#define N_GRAPHS 500
static constexpr float BN_EPS = 1e-5f;

// ---------------------------------------------------------------------------
// Per-destination weighted degree (float) and edge count (int) in one pass.
__global__ void k_degcnt(const int* __restrict__ dst, const float* __restrict__ w,
                         float* __restrict__ wdeg, int* __restrict__ cnt, int E) {
    int i = blockIdx.x * blockDim.x + threadIdx.x;
    if (i < E) {
        int d = dst[i];
        atomicAdd(&wdeg[d], w[i]);
        atomicAdd(&cnt[d], 1);
    }
}

// wdeg -> dinv = rsqrt(wdeg + 1); also per-graph node counts (gcnt pre-zeroed)
__global__ void k_dinv_gcnt(float* __restrict__ wdeg, const int* __restrict__ batch,
                            float* __restrict__ gcnt, int n) {
    int i = blockIdx.x * blockDim.x + threadIdx.x;
    if (i < n) {
        wdeg[i] = rsqrtf(wdeg[i] + 1.0f);
        atomicAdd(&gcnt[batch[i]], 1.0f);
    }
}

// Single-block exclusive scan of cnt[n] -> offs[n+1]; also copies into cursor.
__global__ void k_scan(const int* __restrict__ cnt, int* __restrict__ offs,
                       int* __restrict__ cursor, int n) {
    __shared__ int part[1024];
    int t = threadIdx.x;
    int chunk = (n + 1023) / 1024;
    int base = t * chunk;
    int s = 0;
    for (int k = 0; k < chunk; ++k) {
        int i = base + k;
        if (i < n) s += cnt[i];
    }
    part[t] = s;
    __syncthreads();
    for (int off = 1; off < 1024; off <<= 1) {
        int v = (t >= off) ? part[t - off] : 0;
        __syncthreads();
        part[t] += v;
        __syncthreads();
    }
    int run = (t == 0) ? 0 : part[t - 1];
    for (int k = 0; k < chunk; ++k) {
        int i = base + k;
        if (i < n) {
            offs[i] = run;
            cursor[i] = run;
            run += cnt[i];
        }
    }
    if (t == 1023) offs[n] = run;
}

// Bucket edges into CSR slots; packed entry {src, norm-bits} for one 8B load.
__global__ void k_fill(const int* __restrict__ src, const int* __restrict__ dst,
                       const float* __restrict__ w, const float* __restrict__ dinv,
                       int* __restrict__ cursor, int2* __restrict__ csr, int E) {
    int e = blockIdx.x * blockDim.x + threadIdx.x;
    if (e < E) {
        int s = src[e], d = dst[e];
        int pos = atomicAdd(&cursor[d], 1);
        csr[pos] = make_int2(s, __float_as_int(dinv[s] * w[e] * dinv[d]));
    }
}

// Fold bias+BN of all 3 layers into per-channel affine y = x*kA + kB. 320 thr.
__global__ void k_bnprep_all(
    const float* b1, const float* g1, const float* be1, const float* m1, const float* v1,
    const float* b2, const float* g2, const float* be2, const float* m2, const float* v2,
    const float* b3, const float* g3, const float* be3, const float* m3, const float* v3,
    float* kA1, float* kB1, float* kA2, float* kB2, float* kA3, float* kB3) {
    int t = threadIdx.x;
    if (t < 64) {
        float s = g1[t] * rsqrtf(v1[t] + BN_EPS);
        kA1[t] = s; kB1[t] = (b1[t] - m1[t]) * s + be1[t];
    } else if (t < 192) {
        int c = t - 64;
        float s = g2[c] * rsqrtf(v2[c] + BN_EPS);
        kA2[c] = s; kB2[c] = (b2[c] - m2[c]) * s + be2[c];
    } else if (t < 320) {
        int c = t - 192;
        float s = g3[c] * rsqrtf(v3[c] + BN_EPS);
        kA3[c] = s; kB3[c] = (b3[c] - m3[c]) * s + be3[c];
    }
}

// Layer-1 scalar aggregation: aggx[i] = sum x[src]*nrm + x[i]*dinv^2 (200KB table)
__global__ void k_aggx(const int* __restrict__ offs, const int2* __restrict__ csr,
                       const float* __restrict__ x, const float* __restrict__ dinv,
                       float* __restrict__ aggx, int n) {
    int i = blockIdx.x * blockDim.x + threadIdx.x;
    if (i >= n) return;
    float acc = 0.f;
    int e0 = offs[i], e1 = offs[i + 1];
    for (int j = e0; j < e1; ++j) {
        int2 e = csr[j];
        acc += x[e.x] * __int_as_float(e.y);
    }
    float di = dinv[i];
    aggx[i] = acc + x[i] * di * di;
}

// out1 = relu(affine(aggx * W1))  -> sliced-8 layout [slice][node][8]
__global__ void k_l1(const float* __restrict__ aggx, const float* __restrict__ W1,
                     const float* __restrict__ kA, const float* __restrict__ kB,
                     float* __restrict__ out1s, int n) {
    int gid = blockIdx.x * blockDim.x + threadIdx.x;
    if (gid >= n * 16) return;
    int node = gid >> 4;
    int c4 = (gid & 15) * 4;
    float a = aggx[node];
    float4 wv = *(const float4*)(W1 + c4);
    float4 ka = *(const float4*)(kA + c4);
    float4 kb = *(const float4*)(kB + c4);
    float4 v;
    v.x = fmaxf(a * wv.x * ka.x + kb.x, 0.f);
    v.y = fmaxf(a * wv.y * ka.y + kb.y, 0.f);
    v.z = fmaxf(a * wv.z * ka.z + kb.z, 0.f);
    v.w = fmaxf(a * wv.w * ka.w + kb.w, 0.f);
    *(float4*)(out1s + (size_t)(c4 >> 3) * ((size_t)n * 8) + (size_t)node * 8 + (c4 & 7)) = v;
}

// ---------------------------------------------------------------------------
// Channel-sliced gather: slice = blockIdx%8 -> XCD-local working set.
// Input and output both slice-major: [slice][node][CS]. CS=8 (C=64) or 16 (C=128).
template <int CS>
__global__ void k_gatherS(const int* __restrict__ offs, const int2* __restrict__ csr,
                          const float* __restrict__ Hs, const float* __restrict__ dinv,
                          float* __restrict__ aggs, int n) {
    constexpr int TPN = CS / 4;
    constexpr int NPB = 256 / TPN;
    int slice = blockIdx.x & 7;
    int node = (blockIdx.x >> 3) * NPB + threadIdx.x / TPN;
    if (node >= n) return;
    int cq = (threadIdx.x % TPN) * 4;
    const float* Hb = Hs + (size_t)slice * ((size_t)n * CS);
    float4 acc = {0.f, 0.f, 0.f, 0.f};
    int e0 = offs[node], e1 = offs[node + 1];
    for (int j = e0; j < e1; ++j) {
        int2 e = csr[j];
        float nm = __int_as_float(e.y);
        float4 hv = *(const float4*)(Hb + (size_t)e.x * CS + cq);
        acc.x += hv.x * nm;
        acc.y += hv.y * nm;
        acc.z += hv.z * nm;
        acc.w += hv.w * nm;
    }
    float di = dinv[node];
    float d2 = di * di;
    float4 hv = *(const float4*)(Hb + (size_t)node * CS + cq);
    acc.x += hv.x * d2;
    acc.y += hv.y * d2;
    acc.z += hv.z * d2;
    acc.w += hv.w * d2;
    *(float4*)(aggs + (size_t)slice * ((size_t)n * CS) + (size_t)node * CS + cq) = acc;
}

// out2 = relu(affine(agg2 @ W2))  (agg2 sliced-8 K=64, out sliced-16 C=128)
__global__ void k_mm2(const float* __restrict__ aggs, const float* __restrict__ W,
                      const float* __restrict__ kA, const float* __restrict__ kB,
                      float* __restrict__ outs, int n) {
    int gid = blockIdx.x * blockDim.x + threadIdx.x;
    if (gid >= n * 32) return;
    int node = gid >> 5;
    int c4 = (gid & 31) * 4;
    float4 acc = {0.f, 0.f, 0.f, 0.f};
    for (int kc = 0; kc < 8; ++kc) {
        const float* xc = aggs + (size_t)kc * ((size_t)n * 8) + (size_t)node * 8;
#pragma unroll
        for (int kk = 0; kk < 8; ++kk) {
            float xk = xc[kk];
            float4 wv = *(const float4*)(W + (size_t)(kc * 8 + kk) * 128 + c4);
            acc.x += xk * wv.x;
            acc.y += xk * wv.y;
            acc.z += xk * wv.z;
            acc.w += xk * wv.w;
        }
    }
    float4 ka = *(const float4*)(kA + c4);
    float4 kb = *(const float4*)(kB + c4);
    float4 v;
    v.x = fmaxf(acc.x * ka.x + kb.x, 0.f);
    v.y = fmaxf(acc.y * ka.y + kb.y, 0.f);
    v.z = fmaxf(acc.z * ka.z + kb.z, 0.f);
    v.w = fmaxf(acc.w * ka.w + kb.w, 0.f);
    *(float4*)(outs + (size_t)(c4 >> 4) * ((size_t)n * 16) + (size_t)node * 16 + (c4 & 15)) = v;
}

// out3 = relu(affine(agg3 @ W3)) + res; pooled[batch] += out3 (never stored)
__global__ void k_mm3(const float* __restrict__ aggs, const float* __restrict__ W,
                      const float* __restrict__ kA, const float* __restrict__ kB,
                      const float* __restrict__ res, const int* __restrict__ batch,
                      float* __restrict__ pooled, int n) {
    int gid = blockIdx.x * blockDim.x + threadIdx.x;
    if (gid >= n * 32) return;
    int node = gid >> 5;
    int c4 = (gid & 31) * 4;
    float4 acc = {0.f, 0.f, 0.f, 0.f};
    for (int kc = 0; kc < 8; ++kc) {
        const float* xc = aggs + (size_t)kc * ((size_t)n * 16) + (size_t)node * 16;
#pragma unroll
        for (int kk = 0; kk < 16; ++kk) {
            float xk = xc[kk];
            float4 wv = *(const float4*)(W + (size_t)(kc * 16 + kk) * 128 + c4);
            acc.x += xk * wv.x;
            acc.y += xk * wv.y;
            acc.z += xk * wv.z;
            acc.w += xk * wv.w;
        }
    }
    float4 ka = *(const float4*)(kA + c4);
    float4 kb = *(const float4*)(kB + c4);
    float4 rv = *(const float4*)(res + (size_t)(c4 >> 4) * ((size_t)n * 16) + (size_t)node * 16 + (c4 & 15));
    float4 v;
    v.x = fmaxf(acc.x * ka.x + kb.x, 0.f) + rv.x;
    v.y = fmaxf(acc.y * ka.y + kb.y, 0.f) + rv.y;
    v.z = fmaxf(acc.z * ka.z + kb.z, 0.f) + rv.z;
    v.w = fmaxf(acc.w * ka.w + kb.w, 0.f) + rv.w;
    float* p = pooled + (size_t)batch[node] * 128 + c4;
    atomicAdd(p + 0, v.x);
    atomicAdd(p + 1, v.y);
    atomicAdd(p + 2, v.z);
    atomicAdd(p + 3, v.w);
}

// out[g] = dot(pooled[g,:], Wf) / max(cnt,1) + bf
__global__ void k_final(const float* __restrict__ pooled, const float* __restrict__ gcnt,
                        const float* __restrict__ Wf, const float* __restrict__ bf,
                        float* __restrict__ out, int G) {
    int g = blockIdx.x * blockDim.x + threadIdx.x;
    if (g >= G) return;
    float s = 0.f;
    for (int c = 0; c < 128; ++c) s += pooled[g * 128 + c] * Wf[c];
    out[g] = s / fmaxf(gcnt[g], 1.0f) + bf[0];
}

// ---------------------------------------------------------------------------
extern "C" void kernel_launch(void* const* d_in, const int* in_sizes, int n_in,
                              void* d_out, int out_size, void* d_ws, size_t ws_size,
                              hipStream_t stream) {
    const float* x     = (const float*)d_in[0];
    const int*   ei    = (const int*)d_in[1];
    const int*   src   = ei;
    const int*   dst   = ei + N_EDGES;
    const float* w     = (const float*)d_in[2];
    const int*   batch = (const int*)d_in[3];
    const float* W1 = (const float*)d_in[4];
    const float* b1 = (const float*)d_in[5];
    const float* W2 = (const float*)d_in[6];
    const float* b2 = (const float*)d_in[7];
    const float* W3 = (const float*)d_in[8];
    const float* b3 = (const float*)d_in[9];
    const float* Wf = (const float*)d_in[10];
    const float* bf = (const float*)d_in[11];
    const float* g1 = (const float*)d_in[12];
    const float* be1 = (const float*)d_in[13];
    const float* m1 = (const float*)d_in[14];
    const float* v1 = (const float*)d_in[15];
    const float* g2 = (const float*)d_in[16];
    const float* be2 = (const float*)d_in[17];
    const float* m2 = (const float*)d_in[18];
    const float* v2 = (const float*)d_in[19];
    const float* g3 = (const float*)d_in[20];
    const float* be3 = (const float*)d_in[21];
    const float* m3 = (const float*)d_in[22];
    const float* v3 = (const float*)d_in[23];

    float* out = (float*)d_out;

    // Workspace layout (all sections 16B-aligned)
    float* ws    = (float*)d_ws;
    float* out2s = ws;                                  // N*128 sliced-16 (layer-2 out / residual)
    float* buf2  = out2s + (size_t)N_NODES * 128;       // N*128: [out1s N*64 | agg2s N*64], reused as agg3s
    float* out1s = buf2;
    float* agg2s = buf2 + (size_t)N_NODES * 64;
    float* agg3s = buf2;
    int2*  csr   = (int2*)(buf2 + (size_t)N_NODES * 128); // E
    float* wdeg  = (float*)(csr + N_EDGES);             // N (becomes dinv)
    int*   cnt_i = (int*)(wdeg + N_NODES);              // N
    int*   cursor = cnt_i + N_NODES;                    // N (reused as aggx)
    float* aggx  = (float*)cursor;
    float* kA1   = (float*)(cursor + N_NODES);          // 64
    float* kB1   = kA1 + 64;                            // 64
    float* kA2   = kB1 + 64;                            // 128
    float* kB2   = kA2 + 128;                           // 128
    float* kA3   = kB2 + 128;                           // 128
    float* kB3   = kA3 + 128;                           // 128
    float* pooled = kB3 + 128;                          // G*128
    float* gcnt  = pooled + (size_t)N_GRAPHS * 128;     // G
    int*   offs  = (int*)(gcnt + N_GRAPHS);             // N+1

    const int BS = 256;
    auto nb = [](long n) { return (int)((n + 255) / 256); };

    hipMemsetAsync(wdeg, 0, N_NODES * sizeof(float), stream);
    hipMemsetAsync(cnt_i, 0, N_NODES * sizeof(int), stream);
    hipMemsetAsync(pooled, 0, (size_t)N_GRAPHS * 129 * sizeof(float), stream);

    // --- CSR build + degree norm ---
    k_degcnt<<<nb(N_EDGES), BS, 0, stream>>>(dst, w, wdeg, cnt_i, N_EDGES);
    k_scan<<<1, 1024, 0, stream>>>(cnt_i, offs, cursor, N_NODES);
    k_dinv_gcnt<<<nb(N_NODES), BS, 0, stream>>>(wdeg, batch, gcnt, N_NODES);
    float* dinv = wdeg;
    k_fill<<<nb(N_EDGES), BS, 0, stream>>>(src, dst, w, dinv, cursor, csr, N_EDGES);
    k_bnprep_all<<<1, 320, 0, stream>>>(b1, g1, be1, m1, v1, b2, g2, be2, m2, v2,
                                        b3, g3, be3, m3, v3, kA1, kB1, kA2, kB2, kA3, kB3);

    // --- Layer 1: aggregate scalar x, then 1->64 matmul + affine + relu ---
    k_aggx<<<nb(N_NODES), BS, 0, stream>>>(offs, csr, x, dinv, aggx, N_NODES);
    k_l1<<<nb((long)N_NODES * 16), BS, 0, stream>>>(aggx, W1, kA1, kB1, out1s, N_NODES);

    // --- Layer 2: aggregate 64-wide (sliced), then 64->128 matmul + affine + relu ---
    k_gatherS<8><<<8 * ((N_NODES + 127) / 128), BS, 0, stream>>>(
        offs, csr, out1s, dinv, agg2s, N_NODES);
    k_mm2<<<nb((long)N_NODES * 32), BS, 0, stream>>>(agg2s, W2, kA2, kB2, out2s, N_NODES);

    // --- Layer 3: aggregate 128-wide (sliced), matmul + affine + relu + res + pool ---
    k_gatherS<16><<<8 * ((N_NODES + 63) / 64), BS, 0, stream>>>(
        offs, csr, out2s, dinv, agg3s, N_NODES);
    k_mm3<<<nb((long)N_NODES * 32), BS, 0, stream>>>(agg3s, W3, kA3, kB3, out2s, batch,
                                                     pooled, N_NODES);

    // --- final linear ---
    k_final<<<nb(N_GRAPHS), BS, 0, stream>>>(pooled, gcnt, Wf, bf, out, N_GRAPHS);
}

// Round 4
// 561.617 us; speedup vs baseline: 5.8040x; 1.3344x over previous
//
#include <hip/hip_runtime.h>

#define N_NODES  50000
#define N_EDGES  640000
#define N_GRAPHS 500
static constexpr float BN_EPS = 1e-5f;

// ---------------------------------------------------------------------------
__global__ void k_degcnt(const int* __restrict__ dst, const float* __restrict__ w,
                         float* __restrict__ wdeg, int* __restrict__ cnt, int E) {
    int i = blockIdx.x * blockDim.x + threadIdx.x;
    if (i < E) {
        int d = dst[i];
        atomicAdd(&wdeg[d], w[i]);
        atomicAdd(&cnt[d], 1);
    }
}

__global__ void k_dinv_gcnt(float* __restrict__ wdeg, const int* __restrict__ batch,
                            float* __restrict__ gcnt, int n) {
    int i = blockIdx.x * blockDim.x + threadIdx.x;
    if (i < n) {
        wdeg[i] = rsqrtf(wdeg[i] + 1.0f);
        atomicAdd(&gcnt[batch[i]], 1.0f);
    }
}

__global__ void k_scan(const int* __restrict__ cnt, int* __restrict__ offs,
                       int* __restrict__ cursor, int n) {
    __shared__ int part[1024];
    int t = threadIdx.x;
    int chunk = (n + 1023) / 1024;
    int base = t * chunk;
    int s = 0;
    for (int k = 0; k < chunk; ++k) {
        int i = base + k;
        if (i < n) s += cnt[i];
    }
    part[t] = s;
    __syncthreads();
    for (int off = 1; off < 1024; off <<= 1) {
        int v = (t >= off) ? part[t - off] : 0;
        __syncthreads();
        part[t] += v;
        __syncthreads();
    }
    int run = (t == 0) ? 0 : part[t - 1];
    for (int k = 0; k < chunk; ++k) {
        int i = base + k;
        if (i < n) {
            offs[i] = run;
            cursor[i] = run;
            run += cnt[i];
        }
    }
    if (t == 1023) offs[n] = run;
}

__global__ void k_fill(const int* __restrict__ src, const int* __restrict__ dst,
                       const float* __restrict__ w, const float* __restrict__ dinv,
                       int* __restrict__ cursor, int2* __restrict__ csr, int E) {
    int e = blockIdx.x * blockDim.x + threadIdx.x;
    if (e < E) {
        int s = src[e], d = dst[e];
        int pos = atomicAdd(&cursor[d], 1);
        csr[pos] = make_int2(s, __float_as_int(dinv[s] * w[e] * dinv[d]));
    }
}

// Fold bias+BN into per-channel affine. Layer1 additionally folds W1 (rank-1):
// kA1[c] = W1[c]*g1[c]*rsqrt(v1+eps), so H1 = relu(aggx*kA1 + kB1).
__global__ void k_bnprep_all(
    const float* W1,
    const float* b1, const float* g1, const float* be1, const float* m1, const float* v1,
    const float* b2, const float* g2, const float* be2, const float* m2, const float* v2,
    const float* b3, const float* g3, const float* be3, const float* m3, const float* v3,
    float* kA1, float* kB1, float* kA2, float* kB2, float* kA3, float* kB3) {
    int t = threadIdx.x;
    if (t < 64) {
        float s = g1[t] * rsqrtf(v1[t] + BN_EPS);
        kA1[t] = W1[t] * s;
        kB1[t] = (b1[t] - m1[t]) * s + be1[t];
    } else if (t < 192) {
        int c = t - 64;
        float s = g2[c] * rsqrtf(v2[c] + BN_EPS);
        kA2[c] = s; kB2[c] = (b2[c] - m2[c]) * s + be2[c];
    } else if (t < 320) {
        int c = t - 192;
        float s = g3[c] * rsqrtf(v3[c] + BN_EPS);
        kA3[c] = s; kB3[c] = (b3[c] - m3[c]) * s + be3[c];
    }
}

// Layer-1 scalar aggregation over the 200KB x table.
__global__ void k_aggx(const int* __restrict__ offs, const int2* __restrict__ csr,
                       const float* __restrict__ x, const float* __restrict__ dinv,
                       float* __restrict__ aggx, int n) {
    int i = blockIdx.x * blockDim.x + threadIdx.x;
    if (i >= n) return;
    float acc = 0.f;
    int e0 = offs[i], e1 = offs[i + 1];
    for (int j = e0; j < e1; ++j) {
        int2 e = csr[j];
        acc += x[e.x] * __int_as_float(e.y);
    }
    float di = dinv[i];
    aggx[i] = acc + x[i] * di * di;
}

// ---------------------------------------------------------------------------
// Fused layer-1-matmul + layer-2 aggregation:
// agg2[d][c] = sum_e nm * relu(aggx[src]*kA1[c]+kB1[c]) + d2 * relu(aggx[d]*kA1[c]+kB1[c])
// 16 threads per node (4 ch each). Output plain row-major [node][64].
__global__ void k_gather2F(const int* __restrict__ offs, const int2* __restrict__ csr,
                           const float* __restrict__ aggx, const float* __restrict__ dinv,
                           const float* __restrict__ kA1, const float* __restrict__ kB1,
                           float* __restrict__ agg2, int n) {
    int gid = blockIdx.x * blockDim.x + threadIdx.x;
    int node = gid >> 4;
    if (node >= n) return;
    int c4 = (gid & 15) * 4;
    float4 wa = *(const float4*)(kA1 + c4);
    float4 wb = *(const float4*)(kB1 + c4);
    float4 acc = {0.f, 0.f, 0.f, 0.f};
    int e0 = offs[node], e1 = offs[node + 1];
    for (int j = e0; j < e1; ++j) {
        int2 e = csr[j];
        float a = aggx[e.x];
        float nm = __int_as_float(e.y);
        acc.x += nm * fmaxf(a * wa.x + wb.x, 0.f);
        acc.y += nm * fmaxf(a * wa.y + wb.y, 0.f);
        acc.z += nm * fmaxf(a * wa.z + wb.z, 0.f);
        acc.w += nm * fmaxf(a * wa.w + wb.w, 0.f);
    }
    float di = dinv[node];
    float d2 = di * di;
    float a = aggx[node];
    acc.x += d2 * fmaxf(a * wa.x + wb.x, 0.f);
    acc.y += d2 * fmaxf(a * wa.y + wb.y, 0.f);
    acc.z += d2 * fmaxf(a * wa.z + wb.z, 0.f);
    acc.w += d2 * fmaxf(a * wa.w + wb.w, 0.f);
    *(float4*)(agg2 + (size_t)node * 64 + c4) = acc;
}

// ---------------------------------------------------------------------------
// Channel-sliced gather (layer 3): slice = blockIdx%8 -> XCD-local 3.2MB table.
__global__ void k_gatherS16(const int* __restrict__ offs, const int2* __restrict__ csr,
                            const float* __restrict__ Hs, const float* __restrict__ dinv,
                            float* __restrict__ aggs, int n) {
    int slice = blockIdx.x & 7;
    int node = (blockIdx.x >> 3) * 64 + threadIdx.x / 4;
    if (node >= n) return;
    int cq = (threadIdx.x % 4) * 4;
    const float* Hb = Hs + (size_t)slice * ((size_t)n * 16);
    float4 acc = {0.f, 0.f, 0.f, 0.f};
    int e0 = offs[node], e1 = offs[node + 1];
    for (int j = e0; j < e1; ++j) {
        int2 e = csr[j];
        float nm = __int_as_float(e.y);
        float4 hv = *(const float4*)(Hb + (size_t)e.x * 16 + cq);
        acc.x += hv.x * nm;
        acc.y += hv.y * nm;
        acc.z += hv.z * nm;
        acc.w += hv.w * nm;
    }
    float di = dinv[node];
    float d2 = di * di;
    float4 hv = *(const float4*)(Hb + (size_t)node * 16 + cq);
    acc.x += hv.x * d2;
    acc.y += hv.y * d2;
    acc.z += hv.z * d2;
    acc.w += hv.w * d2;
    *(float4*)(aggs + (size_t)slice * ((size_t)n * 16) + (size_t)node * 16 + cq) = acc;
}

// ---------------------------------------------------------------------------
// Register-tiled matmul: 64 nodes/block, x-tile in LDS, 8 float4 acc/thread.
// Input layout: [S][n][K/S] slice-major (S=1 -> plain row-major).
// Output: !POOL -> sliced-16 [8][n][16]; POOL -> relu+res+segment-pool.
template <int K, int S, bool POOL>
__global__ __launch_bounds__(256) void k_mmT(
    const float* __restrict__ Xs, const float* __restrict__ W,
    const float* __restrict__ kA, const float* __restrict__ kB,
    const float* __restrict__ res, const int* __restrict__ batch,
    float* __restrict__ outs, float* __restrict__ pooled, int n) {
    constexpr int CS = K / S;
    __shared__ float xl[64 * K];
    int base = blockIdx.x * 64;
    int tid = threadIdx.x;
    constexpr int TOT4 = 64 * K / 4;
    constexpr int SL4 = 64 * CS / 4;   // float4s per slice chunk
    for (int i = tid; i < TOT4; i += 256) {
        int slice = i / SL4;
        int rem = i - slice * SL4;
        int nl = rem / (CS / 4);
        int off4 = (rem % (CS / 4)) * 4;
        int node = base + nl;
        float4 v = {0.f, 0.f, 0.f, 0.f};
        if (node < n)
            v = *(const float4*)(Xs + (size_t)slice * ((size_t)n * CS) + (size_t)node * CS + off4);
        *(float4*)(&xl[nl * K + slice * CS + off4]) = v;
    }
    __syncthreads();

    int ct = tid & 31;
    int ng = tid >> 5;
    int c4 = ct * 4;
    float4 acc[8];
#pragma unroll
    for (int i = 0; i < 8; ++i) acc[i] = make_float4(0.f, 0.f, 0.f, 0.f);

    for (int k4 = 0; k4 < K / 4; ++k4) {
        float4 wv0 = *(const float4*)(W + (size_t)(k4 * 4 + 0) * 128 + c4);
        float4 wv1 = *(const float4*)(W + (size_t)(k4 * 4 + 1) * 128 + c4);
        float4 wv2 = *(const float4*)(W + (size_t)(k4 * 4 + 2) * 128 + c4);
        float4 wv3 = *(const float4*)(W + (size_t)(k4 * 4 + 3) * 128 + c4);
#pragma unroll
        for (int i = 0; i < 8; ++i) {
            float4 xv = *(const float4*)(&xl[(ng * 8 + i) * K + k4 * 4]);
            acc[i].x += xv.x * wv0.x; acc[i].y += xv.x * wv0.y;
            acc[i].z += xv.x * wv0.z; acc[i].w += xv.x * wv0.w;
            acc[i].x += xv.y * wv1.x; acc[i].y += xv.y * wv1.y;
            acc[i].z += xv.y * wv1.z; acc[i].w += xv.y * wv1.w;
            acc[i].x += xv.z * wv2.x; acc[i].y += xv.z * wv2.y;
            acc[i].z += xv.z * wv2.z; acc[i].w += xv.z * wv2.w;
            acc[i].x += xv.w * wv3.x; acc[i].y += xv.w * wv3.y;
            acc[i].z += xv.w * wv3.z; acc[i].w += xv.w * wv3.w;
        }
    }

    float4 ka = *(const float4*)(kA + c4);
    float4 kb = *(const float4*)(kB + c4);
#pragma unroll
    for (int i = 0; i < 8; ++i) {
        int node = base + ng * 8 + i;
        float4 a = acc[i];
        float4 v;
        v.x = fmaxf(a.x * ka.x + kb.x, 0.f);
        v.y = fmaxf(a.y * ka.y + kb.y, 0.f);
        v.z = fmaxf(a.z * ka.z + kb.z, 0.f);
        v.w = fmaxf(a.w * ka.w + kb.w, 0.f);
        if (POOL) {
            if (node < n) {
                float4 rv = *(const float4*)(res + (size_t)(c4 >> 4) * ((size_t)n * 16) +
                                             (size_t)node * 16 + (c4 & 15));
                v.x += rv.x; v.y += rv.y; v.z += rv.z; v.w += rv.w;
            }
        }
        acc[i] = v;
    }

    if (POOL) {
        __syncthreads();   // xl reuse as pool buffer
        int g0 = batch[base];
        int glast = batch[(base + 63 < n) ? (base + 63) : (n - 1)];
        int span = glast - g0 + 1;
        if (span <= 64 * K / 128) {
            float* pl = xl;
            for (int idx = tid; idx < span * 128; idx += 256) pl[idx] = 0.f;
            __syncthreads();
#pragma unroll
            for (int i = 0; i < 8; ++i) {
                int node = base + ng * 8 + i;
                if (node < n) {
                    int g = batch[node] - g0;
                    float* p = pl + g * 128 + c4;
                    atomicAdd(p + 0, acc[i].x);
                    atomicAdd(p + 1, acc[i].y);
                    atomicAdd(p + 2, acc[i].z);
                    atomicAdd(p + 3, acc[i].w);
                }
            }
            __syncthreads();
            for (int idx = tid; idx < span * 128; idx += 256)
                atomicAdd(&pooled[g0 * 128 + idx], pl[idx]);
        } else {
#pragma unroll
            for (int i = 0; i < 8; ++i) {
                int node = base + ng * 8 + i;
                if (node < n) {
                    float* p = pooled + (size_t)batch[node] * 128 + c4;
                    atomicAdd(p + 0, acc[i].x);
                    atomicAdd(p + 1, acc[i].y);
                    atomicAdd(p + 2, acc[i].z);
                    atomicAdd(p + 3, acc[i].w);
                }
            }
        }
    } else {
#pragma unroll
        for (int i = 0; i < 8; ++i) {
            int node = base + ng * 8 + i;
            if (node < n)
                *(float4*)(outs + (size_t)(c4 >> 4) * ((size_t)n * 16) +
                           (size_t)node * 16 + (c4 & 15)) = acc[i];
        }
    }
}

__global__ void k_final(const float* __restrict__ pooled, const float* __restrict__ gcnt,
                        const float* __restrict__ Wf, const float* __restrict__ bf,
                        float* __restrict__ out, int G) {
    int g = blockIdx.x * blockDim.x + threadIdx.x;
    if (g >= G) return;
    float s = 0.f;
    for (int c = 0; c < 128; ++c) s += pooled[g * 128 + c] * Wf[c];
    out[g] = s / fmaxf(gcnt[g], 1.0f) + bf[0];
}

// ---------------------------------------------------------------------------
extern "C" void kernel_launch(void* const* d_in, const int* in_sizes, int n_in,
                              void* d_out, int out_size, void* d_ws, size_t ws_size,
                              hipStream_t stream) {
    const float* x     = (const float*)d_in[0];
    const int*   ei    = (const int*)d_in[1];
    const int*   src   = ei;
    const int*   dst   = ei + N_EDGES;
    const float* w     = (const float*)d_in[2];
    const int*   batch = (const int*)d_in[3];
    const float* W1 = (const float*)d_in[4];
    const float* b1 = (const float*)d_in[5];
    const float* W2 = (const float*)d_in[6];
    const float* b2 = (const float*)d_in[7];
    const float* W3 = (const float*)d_in[8];
    const float* b3 = (const float*)d_in[9];
    const float* Wf = (const float*)d_in[10];
    const float* bf = (const float*)d_in[11];
    const float* g1 = (const float*)d_in[12];
    const float* be1 = (const float*)d_in[13];
    const float* m1 = (const float*)d_in[14];
    const float* v1 = (const float*)d_in[15];
    const float* g2 = (const float*)d_in[16];
    const float* be2 = (const float*)d_in[17];
    const float* m2 = (const float*)d_in[18];
    const float* v2 = (const float*)d_in[19];
    const float* g3 = (const float*)d_in[20];
    const float* be3 = (const float*)d_in[21];
    const float* m3 = (const float*)d_in[22];
    const float* v3 = (const float*)d_in[23];

    float* out = (float*)d_out;

    // Workspace layout (all sections 16B-aligned)
    float* ws    = (float*)d_ws;
    float* out2s = ws;                                    // N*128 sliced-16 (layer-2 out / res)
    float* buf2  = out2s + (size_t)N_NODES * 128;         // N*128: agg2 (N*64) then agg3s (N*128)
    float* agg2  = buf2;                                  // plain [node][64]
    float* agg3s = buf2;                                  // sliced-16 (overwrites agg2 later? no—)
    float* agg3s_real = buf2 + 0;                         // see note below
    int2*  csr   = (int2*)(buf2 + (size_t)N_NODES * 128); // E
    float* wdeg  = (float*)(csr + N_EDGES);               // N (becomes dinv)
    int*   cnt_i = (int*)(wdeg + N_NODES);                // N
    int*   cursor = cnt_i + N_NODES;                      // N (reused as aggx)
    float* aggx  = (float*)cursor;
    float* kA1   = (float*)(cursor + N_NODES);            // 64
    float* kB1   = kA1 + 64;                              // 64
    float* kA2   = kB1 + 64;                              // 128
    float* kB2   = kA2 + 128;                             // 128
    float* kA3   = kB2 + 128;                             // 128
    float* kB3   = kA3 + 128;                             // 128
    float* pooled = kB3 + 128;                            // G*128
    float* gcnt  = pooled + (size_t)N_GRAPHS * 128;       // G
    int*   offs  = (int*)(gcnt + N_GRAPHS);               // N+1
    (void)agg3s; (void)agg3s_real;
    // agg2 occupies buf2[0 .. N*64); agg3s uses buf2[0 .. N*128) — agg2 is fully
    // consumed by k_mmT<64> before k_gatherS16 writes agg3s. Safe because they
    // are in different dispatches (stream-ordered).

    const int BS = 256;
    auto nb = [](long n) { return (int)((n + 255) / 256); };

    hipMemsetAsync(wdeg, 0, N_NODES * sizeof(float), stream);
    hipMemsetAsync(cnt_i, 0, N_NODES * sizeof(int), stream);
    hipMemsetAsync(pooled, 0, (size_t)N_GRAPHS * 129 * sizeof(float), stream);

    // --- CSR build + degree norm ---
    k_degcnt<<<nb(N_EDGES), BS, 0, stream>>>(dst, w, wdeg, cnt_i, N_EDGES);
    k_scan<<<1, 1024, 0, stream>>>(cnt_i, offs, cursor, N_NODES);
    k_dinv_gcnt<<<nb(N_NODES), BS, 0, stream>>>(wdeg, batch, gcnt, N_NODES);
    float* dinv = wdeg;
    k_fill<<<nb(N_EDGES), BS, 0, stream>>>(src, dst, w, dinv, cursor, csr, N_EDGES);
    k_bnprep_all<<<1, 320, 0, stream>>>(W1, b1, g1, be1, m1, v1, b2, g2, be2, m2, v2,
                                        b3, g3, be3, m3, v3, kA1, kB1, kA2, kB2, kA3, kB3);

    // --- Layer 1 aggregate (scalar) ---
    k_aggx<<<nb(N_NODES), BS, 0, stream>>>(offs, csr, x, dinv, aggx, N_NODES);

    // --- Layer 2: fused L1-matmul + aggregate, then 64->128 matmul ---
    k_gather2F<<<nb((long)N_NODES * 16), BS, 0, stream>>>(
        offs, csr, aggx, dinv, kA1, kB1, agg2, N_NODES);
    k_mmT<64, 1, false><<<(N_NODES + 63) / 64, BS, 0, stream>>>(
        agg2, W2, kA2, kB2, nullptr, nullptr, out2s, nullptr, N_NODES);

    // --- Layer 3: sliced aggregate, then 128->128 matmul + res + pool ---
    k_gatherS16<<<8 * ((N_NODES + 63) / 64), BS, 0, stream>>>(
        offs, csr, out2s, dinv, buf2, N_NODES);
    k_mmT<128, 8, true><<<(N_NODES + 63) / 64, BS, 0, stream>>>(
        buf2, W3, kA3, kB3, out2s, batch, nullptr, pooled, N_NODES);

    // --- final linear ---
    k_final<<<nb(N_GRAPHS), BS, 0, stream>>>(pooled, gcnt, Wf, bf, out, N_GRAPHS);
}

// Round 5
// 442.163 us; speedup vs baseline: 7.3721x; 1.2702x over previous
//
#include <hip/hip_runtime.h>

#define N_NODES  50000
#define N_EDGES  640000
#define N_GRAPHS 500
static constexpr float BN_EPS = 1e-5f;
#define SCAN_NB ((N_NODES + 255) / 256)   // 196 blocks

// ---------------------------------------------------------------------------
__global__ void k_degcnt(const int* __restrict__ dst, const float* __restrict__ w,
                         float* __restrict__ wdeg, int* __restrict__ cnt, int E) {
    int i = blockIdx.x * blockDim.x + threadIdx.x;
    if (i < E) {
        int d = dst[i];
        atomicAdd(&wdeg[d], w[i]);
        atomicAdd(&cnt[d], 1);
    }
}

__global__ void k_dinv_gcnt(float* __restrict__ wdeg, const int* __restrict__ batch,
                            float* __restrict__ gcnt, int n) {
    int i = blockIdx.x * blockDim.x + threadIdx.x;
    if (i < n) {
        wdeg[i] = rsqrtf(wdeg[i] + 1.0f);
        atomicAdd(&gcnt[batch[i]], 1.0f);
    }
}

// --- 3-phase hierarchical exclusive scan of cnt[N] -> offs[N+1] (+cursor) ---
__global__ void k_scan1(const int* __restrict__ cnt, int* __restrict__ bsum, int n) {
    __shared__ int red[256];
    int i = blockIdx.x * 256 + threadIdx.x;
    red[threadIdx.x] = (i < n) ? cnt[i] : 0;
    __syncthreads();
    for (int off = 128; off > 0; off >>= 1) {
        if (threadIdx.x < off) red[threadIdx.x] += red[threadIdx.x + off];
        __syncthreads();
    }
    if (threadIdx.x == 0) bsum[blockIdx.x] = red[0];
}

__global__ void k_scan2(const int* __restrict__ bsum, int* __restrict__ bpre, int nb) {
    __shared__ int part[256];
    int t = threadIdx.x;
    part[t] = (t < nb) ? bsum[t] : 0;
    __syncthreads();
    for (int off = 1; off < 256; off <<= 1) {
        int v = (t >= off) ? part[t - off] : 0;
        __syncthreads();
        part[t] += v;
        __syncthreads();
    }
    if (t < nb) bpre[t] = (t == 0) ? 0 : part[t - 1];
}

__global__ void k_scan3(const int* __restrict__ cnt, const int* __restrict__ bpre,
                        int* __restrict__ offs, int* __restrict__ cursor, int n) {
    __shared__ int part[256];
    int i = blockIdx.x * 256 + threadIdx.x;
    int t = threadIdx.x;
    int v = (i < n) ? cnt[i] : 0;
    part[t] = v;
    __syncthreads();
    for (int off = 1; off < 256; off <<= 1) {
        int u = (t >= off) ? part[t - off] : 0;
        __syncthreads();
        part[t] += u;
        __syncthreads();
    }
    int excl = bpre[blockIdx.x] + part[t] - v;
    if (i < n) {
        offs[i] = excl;
        cursor[i] = excl;
    }
    if (i == n - 1) offs[n] = N_EDGES;
}

__global__ void k_fill(const int* __restrict__ src, const int* __restrict__ dst,
                       const float* __restrict__ w, const float* __restrict__ dinv,
                       int* __restrict__ cursor, int2* __restrict__ csr, int E) {
    int e = blockIdx.x * blockDim.x + threadIdx.x;
    if (e < E) {
        int s = src[e], d = dst[e];
        int pos = atomicAdd(&cursor[d], 1);
        csr[pos] = make_int2(s, __float_as_int(dinv[s] * w[e] * dinv[d]));
    }
}

// Fold bias+BN into per-channel affine. Layer1 additionally folds W1 (rank-1):
// kA1[c] = W1[c]*g1[c]*rsqrt(v1+eps), so H1 = relu(aggx*kA1 + kB1).
__global__ void k_bnprep_all(
    const float* W1,
    const float* b1, const float* g1, const float* be1, const float* m1, const float* v1,
    const float* b2, const float* g2, const float* be2, const float* m2, const float* v2,
    const float* b3, const float* g3, const float* be3, const float* m3, const float* v3,
    float* kA1, float* kB1, float* kA2, float* kB2, float* kA3, float* kB3) {
    int t = threadIdx.x;
    if (t < 64) {
        float s = g1[t] * rsqrtf(v1[t] + BN_EPS);
        kA1[t] = W1[t] * s;
        kB1[t] = (b1[t] - m1[t]) * s + be1[t];
    } else if (t < 192) {
        int c = t - 64;
        float s = g2[c] * rsqrtf(v2[c] + BN_EPS);
        kA2[c] = s; kB2[c] = (b2[c] - m2[c]) * s + be2[c];
    } else if (t < 320) {
        int c = t - 192;
        float s = g3[c] * rsqrtf(v3[c] + BN_EPS);
        kA3[c] = s; kB3[c] = (b3[c] - m3[c]) * s + be3[c];
    }
}

// Layer-1 scalar aggregation over the 200KB x table.
__global__ void k_aggx(const int* __restrict__ offs, const int2* __restrict__ csr,
                       const float* __restrict__ x, const float* __restrict__ dinv,
                       float* __restrict__ aggx, int n) {
    int i = blockIdx.x * blockDim.x + threadIdx.x;
    if (i >= n) return;
    float acc = 0.f;
    int e0 = offs[i], e1 = offs[i + 1];
    for (int j = e0; j < e1; ++j) {
        int2 e = csr[j];
        acc += x[e.x] * __int_as_float(e.y);
    }
    float di = dinv[i];
    aggx[i] = acc + x[i] * di * di;
}

// ---------------------------------------------------------------------------
// Fused layer-1-matmul + layer-2 aggregation:
// agg2[d][c] = sum_e nm * relu(aggx[src]*kA1[c]+kB1[c]) + d2 * relu(aggx[d]*kA1[c]+kB1[c])
__global__ void k_gather2F(const int* __restrict__ offs, const int2* __restrict__ csr,
                           const float* __restrict__ aggx, const float* __restrict__ dinv,
                           const float* __restrict__ kA1, const float* __restrict__ kB1,
                           float* __restrict__ agg2, int n) {
    int gid = blockIdx.x * blockDim.x + threadIdx.x;
    int node = gid >> 4;
    if (node >= n) return;
    int c4 = (gid & 15) * 4;
    float4 wa = *(const float4*)(kA1 + c4);
    float4 wb = *(const float4*)(kB1 + c4);
    float4 acc = {0.f, 0.f, 0.f, 0.f};
    int e0 = offs[node], e1 = offs[node + 1];
    for (int j = e0; j < e1; ++j) {
        int2 e = csr[j];
        float a = aggx[e.x];
        float nm = __int_as_float(e.y);
        acc.x += nm * fmaxf(a * wa.x + wb.x, 0.f);
        acc.y += nm * fmaxf(a * wa.y + wb.y, 0.f);
        acc.z += nm * fmaxf(a * wa.z + wb.z, 0.f);
        acc.w += nm * fmaxf(a * wa.w + wb.w, 0.f);
    }
    float di = dinv[node];
    float d2 = di * di;
    float a = aggx[node];
    acc.x += d2 * fmaxf(a * wa.x + wb.x, 0.f);
    acc.y += d2 * fmaxf(a * wa.y + wb.y, 0.f);
    acc.z += d2 * fmaxf(a * wa.z + wb.z, 0.f);
    acc.w += d2 * fmaxf(a * wa.w + wb.w, 0.f);
    *(float4*)(agg2 + (size_t)node * 64 + c4) = acc;
}

// ---------------------------------------------------------------------------
// Channel-sliced gather (layer 3): slice = blockIdx%8 -> XCD-local 3.2MB table.
__global__ void k_gatherS16(const int* __restrict__ offs, const int2* __restrict__ csr,
                            const float* __restrict__ Hs, const float* __restrict__ dinv,
                            float* __restrict__ aggs, int n) {
    int slice = blockIdx.x & 7;
    int node = (blockIdx.x >> 3) * 64 + threadIdx.x / 4;
    if (node >= n) return;
    int cq = (threadIdx.x % 4) * 4;
    const float* Hb = Hs + (size_t)slice * ((size_t)n * 16);
    float4 acc = {0.f, 0.f, 0.f, 0.f};
    int e0 = offs[node], e1 = offs[node + 1];
    for (int j = e0; j < e1; ++j) {
        int2 e = csr[j];
        float nm = __int_as_float(e.y);
        float4 hv = *(const float4*)(Hb + (size_t)e.x * 16 + cq);
        acc.x += hv.x * nm;
        acc.y += hv.y * nm;
        acc.z += hv.z * nm;
        acc.w += hv.w * nm;
    }
    float di = dinv[node];
    float d2 = di * di;
    float4 hv = *(const float4*)(Hb + (size_t)node * 16 + cq);
    acc.x += hv.x * d2;
    acc.y += hv.y * d2;
    acc.z += hv.z * d2;
    acc.w += hv.w * d2;
    *(float4*)(aggs + (size_t)slice * ((size_t)n * 16) + (size_t)node * 16 + cq) = acc;
}

// ---------------------------------------------------------------------------
// Register-tiled matmul: 64 nodes/block, x-tile in LDS, 8 float4 acc/thread.
template <int K, int S, bool POOL>
__global__ __launch_bounds__(256) void k_mmT(
    const float* __restrict__ Xs, const float* __restrict__ W,
    const float* __restrict__ kA, const float* __restrict__ kB,
    const float* __restrict__ res, const int* __restrict__ batch,
    float* __restrict__ outs, float* __restrict__ pooled, int n) {
    constexpr int CS = K / S;
    __shared__ float xl[64 * K];
    int base = blockIdx.x * 64;
    int tid = threadIdx.x;
    constexpr int TOT4 = 64 * K / 4;
    constexpr int SL4 = 64 * CS / 4;
    for (int i = tid; i < TOT4; i += 256) {
        int slice = i / SL4;
        int rem = i - slice * SL4;
        int nl = rem / (CS / 4);
        int off4 = (rem % (CS / 4)) * 4;
        int node = base + nl;
        float4 v = {0.f, 0.f, 0.f, 0.f};
        if (node < n)
            v = *(const float4*)(Xs + (size_t)slice * ((size_t)n * CS) + (size_t)node * CS + off4);
        *(float4*)(&xl[nl * K + slice * CS + off4]) = v;
    }
    __syncthreads();

    int ct = tid & 31;
    int ng = tid >> 5;
    int c4 = ct * 4;
    float4 acc[8];
#pragma unroll
    for (int i = 0; i < 8; ++i) acc[i] = make_float4(0.f, 0.f, 0.f, 0.f);

    for (int k4 = 0; k4 < K / 4; ++k4) {
        float4 wv0 = *(const float4*)(W + (size_t)(k4 * 4 + 0) * 128 + c4);
        float4 wv1 = *(const float4*)(W + (size_t)(k4 * 4 + 1) * 128 + c4);
        float4 wv2 = *(const float4*)(W + (size_t)(k4 * 4 + 2) * 128 + c4);
        float4 wv3 = *(const float4*)(W + (size_t)(k4 * 4 + 3) * 128 + c4);
#pragma unroll
        for (int i = 0; i < 8; ++i) {
            float4 xv = *(const float4*)(&xl[(ng * 8 + i) * K + k4 * 4]);
            acc[i].x += xv.x * wv0.x; acc[i].y += xv.x * wv0.y;
            acc[i].z += xv.x * wv0.z; acc[i].w += xv.x * wv0.w;
            acc[i].x += xv.y * wv1.x; acc[i].y += xv.y * wv1.y;
            acc[i].z += xv.y * wv1.z; acc[i].w += xv.y * wv1.w;
            acc[i].x += xv.z * wv2.x; acc[i].y += xv.z * wv2.y;
            acc[i].z += xv.z * wv2.z; acc[i].w += xv.z * wv2.w;
            acc[i].x += xv.w * wv3.x; acc[i].y += xv.w * wv3.y;
            acc[i].z += xv.w * wv3.z; acc[i].w += xv.w * wv3.w;
        }
    }

    float4 ka = *(const float4*)(kA + c4);
    float4 kb = *(const float4*)(kB + c4);
#pragma unroll
    for (int i = 0; i < 8; ++i) {
        int node = base + ng * 8 + i;
        float4 a = acc[i];
        float4 v;
        v.x = fmaxf(a.x * ka.x + kb.x, 0.f);
        v.y = fmaxf(a.y * ka.y + kb.y, 0.f);
        v.z = fmaxf(a.z * ka.z + kb.z, 0.f);
        v.w = fmaxf(a.w * ka.w + kb.w, 0.f);
        if (POOL) {
            if (node < n) {
                float4 rv = *(const float4*)(res + (size_t)(c4 >> 4) * ((size_t)n * 16) +
                                             (size_t)node * 16 + (c4 & 15));
                v.x += rv.x; v.y += rv.y; v.z += rv.z; v.w += rv.w;
            }
        }
        acc[i] = v;
    }

    if (POOL) {
        __syncthreads();
        int g0 = batch[base];
        int glast = batch[(base + 63 < n) ? (base + 63) : (n - 1)];
        int span = glast - g0 + 1;
        if (span <= 64 * K / 128) {
            float* pl = xl;
            for (int idx = tid; idx < span * 128; idx += 256) pl[idx] = 0.f;
            __syncthreads();
#pragma unroll
            for (int i = 0; i < 8; ++i) {
                int node = base + ng * 8 + i;
                if (node < n) {
                    int g = batch[node] - g0;
                    float* p = pl + g * 128 + c4;
                    atomicAdd(p + 0, acc[i].x);
                    atomicAdd(p + 1, acc[i].y);
                    atomicAdd(p + 2, acc[i].z);
                    atomicAdd(p + 3, acc[i].w);
                }
            }
            __syncthreads();
            for (int idx = tid; idx < span * 128; idx += 256)
                atomicAdd(&pooled[g0 * 128 + idx], pl[idx]);
        } else {
#pragma unroll
            for (int i = 0; i < 8; ++i) {
                int node = base + ng * 8 + i;
                if (node < n) {
                    float* p = pooled + (size_t)batch[node] * 128 + c4;
                    atomicAdd(p + 0, acc[i].x);
                    atomicAdd(p + 1, acc[i].y);
                    atomicAdd(p + 2, acc[i].z);
                    atomicAdd(p + 3, acc[i].w);
                }
            }
        }
    } else {
#pragma unroll
        for (int i = 0; i < 8; ++i) {
            int node = base + ng * 8 + i;
            if (node < n)
                *(float4*)(outs + (size_t)(c4 >> 4) * ((size_t)n * 16) +
                           (size_t)node * 16 + (c4 & 15)) = acc[i];
        }
    }
}

__global__ void k_final(const float* __restrict__ pooled, const float* __restrict__ gcnt,
                        const float* __restrict__ Wf, const float* __restrict__ bf,
                        float* __restrict__ out, int G) {
    int g = blockIdx.x * blockDim.x + threadIdx.x;
    if (g >= G) return;
    float s = 0.f;
    for (int c = 0; c < 128; ++c) s += pooled[g * 128 + c] * Wf[c];
    out[g] = s / fmaxf(gcnt[g], 1.0f) + bf[0];
}

// ---------------------------------------------------------------------------
extern "C" void kernel_launch(void* const* d_in, const int* in_sizes, int n_in,
                              void* d_out, int out_size, void* d_ws, size_t ws_size,
                              hipStream_t stream) {
    const float* x     = (const float*)d_in[0];
    const int*   ei    = (const int*)d_in[1];
    const int*   src   = ei;
    const int*   dst   = ei + N_EDGES;
    const float* w     = (const float*)d_in[2];
    const int*   batch = (const int*)d_in[3];
    const float* W1 = (const float*)d_in[4];
    const float* b1 = (const float*)d_in[5];
    const float* W2 = (const float*)d_in[6];
    const float* b2 = (const float*)d_in[7];
    const float* W3 = (const float*)d_in[8];
    const float* b3 = (const float*)d_in[9];
    const float* Wf = (const float*)d_in[10];
    const float* bf = (const float*)d_in[11];
    const float* g1 = (const float*)d_in[12];
    const float* be1 = (const float*)d_in[13];
    const float* m1 = (const float*)d_in[14];
    const float* v1 = (const float*)d_in[15];
    const float* g2 = (const float*)d_in[16];
    const float* be2 = (const float*)d_in[17];
    const float* m2 = (const float*)d_in[18];
    const float* v2 = (const float*)d_in[19];
    const float* g3 = (const float*)d_in[20];
    const float* be3 = (const float*)d_in[21];
    const float* m3 = (const float*)d_in[22];
    const float* v3 = (const float*)d_in[23];

    float* out = (float*)d_out;

    // Workspace layout (all sections 16B-aligned)
    float* ws    = (float*)d_ws;
    float* out2s = ws;                                    // N*128 sliced-16 (layer-2 out / res)
    float* buf2  = out2s + (size_t)N_NODES * 128;         // N*128: agg2 (N*64) then agg3s
    float* agg2  = buf2;                                  // plain [node][64]
    int2*  csr   = (int2*)(buf2 + (size_t)N_NODES * 128); // E
    float* wdeg  = (float*)(csr + N_EDGES);               // N (becomes dinv)
    int*   cnt_i = (int*)(wdeg + N_NODES);                // N
    int*   cursor = cnt_i + N_NODES;                      // N (reused as aggx)
    float* aggx  = (float*)cursor;
    float* kA1   = (float*)(cursor + N_NODES);            // 64
    float* kB1   = kA1 + 64;                              // 64
    float* kA2   = kB1 + 64;                              // 128
    float* kB2   = kA2 + 128;                             // 128
    float* kA3   = kB2 + 128;                             // 128
    float* kB3   = kA3 + 128;                             // 128
    float* pooled = kB3 + 128;                            // G*128
    float* gcnt  = pooled + (size_t)N_GRAPHS * 128;       // G
    int*   offs  = (int*)(gcnt + N_GRAPHS);               // N+1
    int*   bsum  = offs + N_NODES + 1;                    // SCAN_NB
    int*   bpre  = bsum + SCAN_NB;                        // SCAN_NB

    const int BS = 256;
    auto nb = [](long n) { return (int)((n + 255) / 256); };

    hipMemsetAsync(wdeg, 0, N_NODES * sizeof(float), stream);
    hipMemsetAsync(cnt_i, 0, N_NODES * sizeof(int), stream);
    hipMemsetAsync(pooled, 0, (size_t)N_GRAPHS * 129 * sizeof(float), stream);

    // --- CSR build + degree norm ---
    k_degcnt<<<nb(N_EDGES), BS, 0, stream>>>(dst, w, wdeg, cnt_i, N_EDGES);
    k_scan1<<<SCAN_NB, 256, 0, stream>>>(cnt_i, bsum, N_NODES);
    k_scan2<<<1, 256, 0, stream>>>(bsum, bpre, SCAN_NB);
    k_scan3<<<SCAN_NB, 256, 0, stream>>>(cnt_i, bpre, offs, cursor, N_NODES);
    k_dinv_gcnt<<<nb(N_NODES), BS, 0, stream>>>(wdeg, batch, gcnt, N_NODES);
    float* dinv = wdeg;
    k_fill<<<nb(N_EDGES), BS, 0, stream>>>(src, dst, w, dinv, cursor, csr, N_EDGES);
    k_bnprep_all<<<1, 320, 0, stream>>>(W1, b1, g1, be1, m1, v1, b2, g2, be2, m2, v2,
                                        b3, g3, be3, m3, v3, kA1, kB1, kA2, kB2, kA3, kB3);

    // --- Layer 1 aggregate (scalar) ---
    k_aggx<<<nb(N_NODES), BS, 0, stream>>>(offs, csr, x, dinv, aggx, N_NODES);

    // --- Layer 2: fused L1-matmul + aggregate, then 64->128 matmul ---
    k_gather2F<<<nb((long)N_NODES * 16), BS, 0, stream>>>(
        offs, csr, aggx, dinv, kA1, kB1, agg2, N_NODES);
    k_mmT<64, 1, false><<<(N_NODES + 63) / 64, BS, 0, stream>>>(
        agg2, W2, kA2, kB2, nullptr, nullptr, out2s, nullptr, N_NODES);

    // --- Layer 3: sliced aggregate, then 128->128 matmul + res + pool ---
    k_gatherS16<<<8 * ((N_NODES + 63) / 64), BS, 0, stream>>>(
        offs, csr, out2s, dinv, buf2, N_NODES);
    k_mmT<128, 8, true><<<(N_NODES + 63) / 64, BS, 0, stream>>>(
        buf2, W3, kA3, kB3, out2s, batch, nullptr, pooled, N_NODES);

    // --- final linear ---
    k_final<<<nb(N_GRAPHS), BS, 0, stream>>>(pooled, gcnt, Wf, bf, out, N_GRAPHS);
}